// Round 13
// baseline (489.914 us; speedup 1.0000x reference)
//
#include <hip/hip_runtime.h>

#define NN 100000
#define NE 1600000
#define D  128
#define NG 128
#define NO 16
#define NBUK 391  // dst>>8 buckets: 391*256 >= NN
#define G3 256    // blocks for hist/scatter; G3 * 6250 == NE

typedef unsigned short ushort_t;
typedef __attribute__((ext_vector_type(8))) short short8;
typedef __attribute__((ext_vector_type(4))) float f32x4;

__device__ inline unsigned short f2bf(float f) {  // RNE float->bf16
  unsigned u = __float_as_uint(f);
  unsigned r = u + 0x7fffu + ((u >> 16) & 1u);
  return (unsigned short)(r >> 16);
}
__device__ inline unsigned pk2(float a, float b) {
  return (unsigned)f2bf(a) | ((unsigned)f2bf(b) << 16);
}
__device__ inline float bflo(unsigned q) { return __uint_as_float(q << 16); }
__device__ inline float bfhi(unsigned q) { return __uint_as_float(q & 0xffff0000u); }

// ---------------- utility ----------------
__global__ void k_zero(float* __restrict__ p, int n4) {
  int i = blockIdx.x * blockDim.x + threadIdx.x;
  float4 z = make_float4(0.f, 0.f, 0.f, 0.f);
  for (; i < n4; i += gridDim.x * blockDim.x) ((float4*)p)[i] = z;
}

// ---------------- bucketed CSR build ----------------
__global__ __launch_bounds__(256) void f_hist(const int* __restrict__ dst,
                                              int* __restrict__ bsumG) {
  __shared__ int h[NBUK];
  for (int i = threadIdx.x; i < NBUK; i += 256) h[i] = 0;
  __syncthreads();
  int lo = blockIdx.x * (NE / G3), hi = lo + (NE / G3);
  for (int e = lo + threadIdx.x; e < hi; e += 256) atomicAdd(&h[dst[e] >> 8], 1);
  __syncthreads();
  for (int i = threadIdx.x; i < NBUK; i += 256)
    if (h[i]) atomicAdd(&bsumG[i], h[i]);
}

__global__ __launch_bounds__(512) void f_bscan(const int* __restrict__ bsumG,
                                               int* __restrict__ bbase,
                                               int* __restrict__ bfill,
                                               int* __restrict__ row_ptr) {
  __shared__ int s[512];
  int t = threadIdx.x;
  int v = (t < NBUK) ? bsumG[t] : 0;
  s[t] = v;
  __syncthreads();
  for (int d = 1; d < 512; d <<= 1) {
    int x = (t >= d) ? s[t - d] : 0;
    __syncthreads();
    s[t] += x;
    __syncthreads();
  }
  if (t < NBUK) {
    int e = s[t] - v;
    bbase[t] = e;
    bfill[t] = e;
  }
  if (t == NBUK - 1) bbase[NBUK] = s[t];  // == NE
  if (t == 0) row_ptr[NN] = NE;
}

// pack: src (low 20 bits) | dst-low-8 (bits 20..27)
__global__ __launch_bounds__(256) void f_scatter(const int* __restrict__ src,
                                                 const int* __restrict__ dst,
                                                 int* __restrict__ bfill,
                                                 unsigned* __restrict__ ebuf) {
  __shared__ int h[NBUK];
  __shared__ int base[NBUK];
  for (int i = threadIdx.x; i < NBUK; i += 256) h[i] = 0;
  __syncthreads();
  int lo = blockIdx.x * (NE / G3), hi = lo + (NE / G3);
  for (int e = lo + threadIdx.x; e < hi; e += 256) atomicAdd(&h[dst[e] >> 8], 1);
  __syncthreads();
  for (int i = threadIdx.x; i < NBUK; i += 256) {
    int c = h[i];
    base[i] = c ? atomicAdd(&bfill[i], c) : 0;
  }
  __syncthreads();
  for (int i = threadIdx.x; i < NBUK; i += 256) h[i] = 0;
  __syncthreads();
  for (int e = lo + threadIdx.x; e < hi; e += 256) {
    int d = dst[e];
    int b = d >> 8;
    int k = atomicAdd(&h[b], 1);
    ebuf[base[b] + k] = (unsigned)src[e] | ((unsigned)(d & 255) << 20);
  }
}

// one block per bucket: count -> in-block scan -> row_ptr/inv -> CSR fill
__global__ __launch_bounds__(256) void f_csr(const unsigned* __restrict__ ebuf,
                                             const int* __restrict__ bbase,
                                             int* __restrict__ row_ptr,
                                             float* __restrict__ inv,
                                             int* __restrict__ eidx) {
  __shared__ int c[256];
  __shared__ int rp[256];
  __shared__ int wsum[4];
  int b = blockIdx.x;
  int t = threadIdx.x;
  c[t] = 0;
  __syncthreads();
  int lo = bbase[b], hi = bbase[b + 1];
  for (int i = lo + t; i < hi; i += 256) atomicAdd(&c[ebuf[i] >> 20], 1);
  __syncthreads();
  int cnt = c[t];
  int lane = t & 63;
  int incl = cnt;
#pragma unroll
  for (int d = 1; d < 64; d <<= 1) {
    int x = __shfl_up(incl, d);
    if (lane >= d) incl += x;
  }
  if (lane == 63) wsum[t >> 6] = incl;
  __syncthreads();
  int excl = incl - cnt;
  int w = t >> 6;
#pragma unroll
  for (int i = 0; i < 4; i++) excl += (i < w) ? wsum[i] : 0;
  int rpv = bbase[b] + excl;
  rp[t] = rpv;
  int n = (b << 8) + t;
  if (n < NN) {
    row_ptr[n] = rpv;
    inv[n] = 1.f / (float)(cnt + 1);
  }
  c[t] = 0;  // reuse as fill counters
  __syncthreads();
  for (int i = lo + t; i < hi; i += 256) {
    unsigned p = ebuf[i];
    int dl = p >> 20;
    int k = atomicAdd(&c[dl], 1);
    eidx[rp[dl] + k] = (int)(p & 0xFFFFFu);
  }
}

// ---------------- W1/W2/W3 [128k][128n] f32 -> Wt hi/lo bf16 [n][k] ----------------
__global__ void k_wconv3(const float* __restrict__ W1, const float* __restrict__ W2,
                         const float* __restrict__ W3, ushort_t* __restrict__ Wt) {
  int idx = blockIdx.x * 256 + threadIdx.x;  // 0..49151
  if (idx >= 3 * D * D) return;
  int m = idx / (D * D);
  int r = idx - m * (D * D);
  const float* W = (m == 0) ? W1 : (m == 1) ? W2 : W3;
  ushort_t* hip = Wt + m * 2 * D * D;
  ushort_t* lop = hip + D * D;
  int k = r >> 7, n = r & 127;
  float w = W[r];
  unsigned short h = f2bf(w);
  float hw = __uint_as_float((unsigned)h << 16);
  hip[n * D + k] = h;
  lop[n * D + k] = f2bf(w - hw);
}

// ---------------- gather0: layer-1 gather reading f32 x directly ----------------
// 32 lanes per node, one float4 per lane; 8 row-loads in flight. bf16 agg out.
__global__ __launch_bounds__(256) void k_gather0(
    const float4* __restrict__ x4, const int* __restrict__ rp,
    const int* __restrict__ eidx, const float* __restrict__ inv,
    uint2* __restrict__ aggb2) {
  int t = blockIdx.x * 256 + threadIdx.x;
  int n = t >> 5;
  int l = t & 31;
  if (n >= NN) return;
  int s0 = rp[n], s1 = rp[n + 1];

  float4 a0 = x4[(size_t)n * 32 + l];  // self
  float4 a1 = make_float4(0.f, 0.f, 0.f, 0.f);
  float4 a2 = make_float4(0.f, 0.f, 0.f, 0.f);
  float4 a3 = make_float4(0.f, 0.f, 0.f, 0.f);

  int i = s0;
  for (; i + 8 <= s1; i += 8) {
    int u[8];
    float4 q[8];
#pragma unroll
    for (int j = 0; j < 8; j++) u[j] = eidx[i + j];
#pragma unroll
    for (int j = 0; j < 8; j++) q[j] = x4[(size_t)u[j] * 32 + l];
#pragma unroll
    for (int j = 0; j < 8; j += 4) {
      a0.x += q[j].x; a0.y += q[j].y; a0.z += q[j].z; a0.w += q[j].w;
      a1.x += q[j + 1].x; a1.y += q[j + 1].y; a1.z += q[j + 1].z; a1.w += q[j + 1].w;
      a2.x += q[j + 2].x; a2.y += q[j + 2].y; a2.z += q[j + 2].z; a2.w += q[j + 2].w;
      a3.x += q[j + 3].x; a3.y += q[j + 3].y; a3.z += q[j + 3].z; a3.w += q[j + 3].w;
    }
  }
  for (; i < s1; i++) {
    float4 q = x4[(size_t)eidx[i] * 32 + l];
    a0.x += q.x; a0.y += q.y; a0.z += q.z; a0.w += q.w;
  }

  float iv = inv[n];
  float rx = (a0.x + a1.x + a2.x + a3.x) * iv;
  float ry = (a0.y + a1.y + a2.y + a3.y) * iv;
  float rz = (a0.z + a1.z + a2.z + a3.z) * iv;
  float rw = (a0.w + a1.w + a2.w + a3.w) * iv;
  aggb2[(size_t)n * 32 + l] = make_uint2(pk2(rx, ry), pk2(rz, rw));
}

// ---------------- gather: aggb[n] = bf16((sum_{u->n} hb[u] + hb[n]) * inv[n]) ----------------
// 16 lanes per node, one uint4 (8 bf16) per lane; 8 row-loads in flight.
// At its measured fabric floor (~188MB @ 3.6TB/s) — do not reshape.
__global__ __launch_bounds__(256) void k_gather(
    const uint4* __restrict__ hb4, const int* __restrict__ rp,
    const int* __restrict__ eidx, const float* __restrict__ inv,
    uint4* __restrict__ aggb4) {
  int t = blockIdx.x * 256 + threadIdx.x;
  int n = t >> 4;
  int l = t & 15;
  if (n >= NN) return;
  int s0 = rp[n], s1 = rp[n + 1];

  uint4 sq = hb4[(size_t)n * 16 + l];  // self
  float A0 = bflo(sq.x), A1 = bfhi(sq.x), A2 = bflo(sq.y), A3 = bfhi(sq.y);
  float A4 = bflo(sq.z), A5 = bfhi(sq.z), A6 = bflo(sq.w), A7 = bfhi(sq.w);
  float B0 = 0, B1 = 0, B2 = 0, B3 = 0, B4 = 0, B5 = 0, B6 = 0, B7 = 0;

  int i = s0;
  for (; i + 8 <= s1; i += 8) {
    int u[8];
    uint4 q[8];
#pragma unroll
    for (int j = 0; j < 8; j++) u[j] = eidx[i + j];
#pragma unroll
    for (int j = 0; j < 8; j++) q[j] = hb4[(size_t)u[j] * 16 + l];
#pragma unroll
    for (int j = 0; j < 8; j += 2) {
      A0 += bflo(q[j].x); A1 += bfhi(q[j].x); A2 += bflo(q[j].y); A3 += bfhi(q[j].y);
      A4 += bflo(q[j].z); A5 += bfhi(q[j].z); A6 += bflo(q[j].w); A7 += bfhi(q[j].w);
      B0 += bflo(q[j + 1].x); B1 += bfhi(q[j + 1].x); B2 += bflo(q[j + 1].y); B3 += bfhi(q[j + 1].y);
      B4 += bflo(q[j + 1].z); B5 += bfhi(q[j + 1].z); B6 += bflo(q[j + 1].w); B7 += bfhi(q[j + 1].w);
    }
  }
  for (; i + 2 <= s1; i += 2) {
    uint4 qa = hb4[(size_t)eidx[i] * 16 + l];
    uint4 qb = hb4[(size_t)eidx[i + 1] * 16 + l];
    A0 += bflo(qa.x); A1 += bfhi(qa.x); A2 += bflo(qa.y); A3 += bfhi(qa.y);
    A4 += bflo(qa.z); A5 += bfhi(qa.z); A6 += bflo(qa.w); A7 += bfhi(qa.w);
    B0 += bflo(qb.x); B1 += bfhi(qb.x); B2 += bflo(qb.y); B3 += bfhi(qb.y);
    B4 += bflo(qb.z); B5 += bfhi(qb.z); B6 += bflo(qb.w); B7 += bfhi(qb.w);
  }
  if (i < s1) {
    uint4 q = hb4[(size_t)eidx[i] * 16 + l];
    A0 += bflo(q.x); A1 += bfhi(q.x); A2 += bflo(q.y); A3 += bfhi(q.y);
    A4 += bflo(q.z); A5 += bfhi(q.z); A6 += bflo(q.w); A7 += bfhi(q.w);
  }

  float iv = inv[n];
  uint4 o;
  o.x = pk2((A0 + B0) * iv, (A1 + B1) * iv);
  o.y = pk2((A2 + B2) * iv, (A3 + B3) * iv);
  o.z = pk2((A4 + B4) * iv, (A5 + B5) * iv);
  o.w = pk2((A6 + B6) * iv, (A7 + B7) * iv);
  aggb4[(size_t)n * 16 + l] = o;
}

// ---------------- MFMA GEMM v4 (layers 1,2): out = relu(A @ (Whi+Wlo) + b) ----
// W preloaded to regs as A-operand (frag row = out-col); act staged to swizzled
// LDS, read per-rt as B-operand (frag col = node). Packed 8B stores.
template <int RELU>
__global__ __launch_bounds__(256) void k_mfma(
    const ushort_t* __restrict__ A, const ushort_t* __restrict__ Whi,
    const ushort_t* __restrict__ Wlo, const float* __restrict__ bias,
    ushort_t* __restrict__ outb) {
  __shared__ ushort_t sA[64 * 128];  // 16 KB, XOR slot-swizzled
  int t = threadIdx.x;
  int w = t >> 6;
  int l = t & 63;
  int m = l & 15;
  int seg = l >> 4;
  int R0 = blockIdx.x * 64;

  short8 Wh[2][4], Wl[2][4];
#pragma unroll
  for (int cb2 = 0; cb2 < 2; cb2++) {
    int col = (w * 2 + cb2) * 16 + m;
    const ushort_t* ph = Whi + (size_t)col * D + seg * 8;
    const ushort_t* pl = Wlo + (size_t)col * D + seg * 8;
#pragma unroll
    for (int kc = 0; kc < 4; kc++) {
      Wh[cb2][kc] = *(const short8*)(ph + kc * 32);
      Wl[cb2][kc] = *(const short8*)(pl + kc * 32);
    }
  }

#pragma unroll
  for (int r = 0; r < 4; r++) {
    int q = t + r * 256;
    int row = q >> 4;
    int slot = q & 15;
    float4 v = *(const float4*)(A + (size_t)(R0 + row) * D + slot * 8);
    int sl = slot ^ (row & 15);
    *(float4*)&sA[row * 128 + sl * 8] = v;
  }
  __syncthreads();

#pragma unroll
  for (int rt = 0; rt < 4; rt++) {
    int row = rt * 16 + m;
    short8 act[4];
#pragma unroll
    for (int kc = 0; kc < 4; kc++) {
      int sl = (kc * 4 + seg) ^ m;
      act[kc] = *(const short8*)&sA[row * 128 + sl * 8];
    }
    int node = R0 + row;
#pragma unroll
    for (int cb2 = 0; cb2 < 2; cb2++) {
      f32x4 acc = {0.f, 0.f, 0.f, 0.f};
#pragma unroll
      for (int kc = 0; kc < 4; kc++)
        acc = __builtin_amdgcn_mfma_f32_16x16x32_bf16(Wh[cb2][kc], act[kc], acc, 0, 0, 0);
#pragma unroll
      for (int kc = 0; kc < 4; kc++)
        acc = __builtin_amdgcn_mfma_f32_16x16x32_bf16(Wl[cb2][kc], act[kc], acc, 0, 0, 0);
      if (node < NN) {
        int colb = (w * 2 + cb2) * 16 + seg * 4;
        float4 b4 = *(const float4*)&bias[colb];
        float v0 = acc[0] + b4.x;
        float v1 = acc[1] + b4.y;
        float v2 = acc[2] + b4.z;
        float v3 = acc[3] + b4.w;
        if (RELU) {
          v0 = fmaxf(v0, 0.f); v1 = fmaxf(v1, 0.f);
          v2 = fmaxf(v2, 0.f); v3 = fmaxf(v3, 0.f);
        }
        *(uint2*)&outb[(size_t)node * D + colb] = make_uint2(pk2(v0, v1), pk2(v2, v3));
      }
    }
  }
}

// ---------------- layer 3 + readout fused ----------------
// h3 tile never leaves the block: MFMA -> f32 vals -> gate (LDS reduce) ->
// weighted accumulation into per-block LDS per-graph acc -> one atomic flush.
// gid is sorted so a 64-node block spans few graphs (fallback if > 8).
__global__ __launch_bounds__(256) void k_mfma_ro(
    const ushort_t* __restrict__ A, const ushort_t* __restrict__ Whi,
    const ushort_t* __restrict__ Wlo, const float* __restrict__ bias,
    const int* __restrict__ gid, const float* __restrict__ Wv,
    const float* __restrict__ bv, float* __restrict__ num,
    float* __restrict__ den) {
  __shared__ ushort_t sH[64 * 132];   // bf16 h3 tile, +4 pad
  __shared__ float sg[64][17];        // gate partials
  __shared__ float accg[8][128];      // per-graph accumulators
  __shared__ float dacc[8];
  __shared__ float wl[64];
  __shared__ int gl[64];

  int t = threadIdx.x;
  int w = t >> 6;
  int l = t & 63;
  int m = l & 15;
  int seg = l >> 4;
  int R0 = blockIdx.x * 64;

  // W fragments (regs)
  short8 Wh[2][4], Wl_[2][4];
#pragma unroll
  for (int cb2 = 0; cb2 < 2; cb2++) {
    int col = (w * 2 + cb2) * 16 + m;
    const ushort_t* ph = Whi + (size_t)col * D + seg * 8;
    const ushort_t* pl = Wlo + (size_t)col * D + seg * 8;
#pragma unroll
    for (int kc = 0; kc < 4; kc++) {
      Wh[cb2][kc] = *(const short8*)(ph + kc * 32);
      Wl_[cb2][kc] = *(const short8*)(pl + kc * 32);
    }
  }
  // act fragments: direct global 16B loads (no LDS staging; sH is output tile)
  short8 act[4][4];
#pragma unroll
  for (int rt = 0; rt < 4; rt++) {
    const ushort_t* ar = A + (size_t)(R0 + rt * 16 + m) * D + seg * 8;
#pragma unroll
    for (int kc = 0; kc < 4; kc++)
      act[rt][kc] = *(const short8*)(ar + kc * 32);
  }
  float4 wv4[2];
#pragma unroll
  for (int cb2 = 0; cb2 < 2; cb2++)
    wv4[cb2] = *(const float4*)&Wv[(w * 2 + cb2) * 16 + seg * 4];

#pragma unroll
  for (int rt = 0; rt < 4; rt++) {
    int row = rt * 16 + m;
    float gp = 0.f;
#pragma unroll
    for (int cb2 = 0; cb2 < 2; cb2++) {
      f32x4 acc = {0.f, 0.f, 0.f, 0.f};
#pragma unroll
      for (int kc = 0; kc < 4; kc++)
        acc = __builtin_amdgcn_mfma_f32_16x16x32_bf16(Wh[cb2][kc], act[rt][kc], acc, 0, 0, 0);
#pragma unroll
      for (int kc = 0; kc < 4; kc++)
        acc = __builtin_amdgcn_mfma_f32_16x16x32_bf16(Wl_[cb2][kc], act[rt][kc], acc, 0, 0, 0);
      int colb = (w * 2 + cb2) * 16 + seg * 4;
      float4 b4 = *(const float4*)&bias[colb];
      float v0 = acc[0] + b4.x;
      float v1 = acc[1] + b4.y;
      float v2 = acc[2] + b4.z;
      float v3 = acc[3] + b4.w;
      gp += v0 * wv4[cb2].x + v1 * wv4[cb2].y + v2 * wv4[cb2].z + v3 * wv4[cb2].w;
      *(uint2*)&sH[row * 132 + colb] = make_uint2(pk2(v0, v1), pk2(v2, v3));
    }
    sg[row][w * 4 + seg] = gp;
  }
  __syncthreads();

  // zero accumulators; gate per node
  {
    float* af = (float*)accg;
#pragma unroll
    for (int k = 0; k < 4; k++) af[t + 256 * k] = 0.f;
    if (t < 8) dacc[t] = 0.f;
    if (t < 64) {
      float s = 0.f;
#pragma unroll
      for (int j = 0; j < 16; j++) s += sg[t][j];
      int node = R0 + t;
      float wv = 0.f;
      if (node < NN) wv = 1.f / (1.f + expf(-(s + bv[0])));
      wl[t] = wv;
      gl[t] = gid[node < NN ? node : (NN - 1)];
    }
  }
  __syncthreads();

  int gmin = gl[0];
  int spread = gl[63] - gmin + 1;
  int r = t & 63;
  int c0 = (t >> 6) * 32;
  float wn = wl[r];
  if (spread <= 8) {
    if (t < 64 && wn != 0.f) atomicAdd(&dacc[gl[t] - gmin], wn);
    if (wn != 0.f) {
      int gs = gl[r] - gmin;
#pragma unroll
      for (int cc = 0; cc < 16; cc++) {
        unsigned q = *(const unsigned*)&sH[r * 132 + c0 + cc * 2];
        atomicAdd(&accg[gs][c0 + cc * 2], wn * bflo(q));
        atomicAdd(&accg[gs][c0 + cc * 2 + 1], wn * bfhi(q));
      }
    }
    __syncthreads();
    if (t < 128) {
      for (int g = 0; g < spread; g++) {
        float v = accg[g][t];
        if (v != 0.f) unsafeAtomicAdd(&num[(size_t)(gmin + g) * D + t], v);
      }
    }
    if (t < spread) {
      float v = dacc[t];
      if (v != 0.f) unsafeAtomicAdd(&den[gmin + t], v);
    }
  } else {  // degenerate fallback: direct global atomics
    if (wn != 0.f) {
      int g = gl[r];
#pragma unroll
      for (int cc = 0; cc < 16; cc++) {
        unsigned q = *(const unsigned*)&sH[r * 132 + c0 + cc * 2];
        unsafeAtomicAdd(&num[(size_t)g * D + c0 + cc * 2], wn * bflo(q));
        unsafeAtomicAdd(&num[(size_t)g * D + c0 + cc * 2 + 1], wn * bfhi(q));
      }
    }
    if (t < 64 && wl[t] != 0.f) unsafeAtomicAdd(&den[gl[t]], wl[t]);
  }
}

// ---------------- final ----------------
__global__ void k_final(const float* __restrict__ num, const float* __restrict__ den,
                        const float* __restrict__ Wc, const float* __restrict__ bc,
                        float* __restrict__ out) {
  int t = threadIdx.x;
  int o = t & 15;
  for (int g = t >> 4; g < NG; g += 16) {
    float s = 0.f;
    const float* np = num + (size_t)g * D;
#pragma unroll 8
    for (int c = 0; c < D; c++) s += np[c] * Wc[c * NO + o];
    out[g * NO + o] = s / den[g] + bc[o];
  }
}

// ---------------- launch ----------------
extern "C" void kernel_launch(void* const* d_in, const int* in_sizes, int n_in,
                              void* d_out, int out_size, void* d_ws, size_t ws_size,
                              hipStream_t stream) {
  const float* x   = (const float*)d_in[0];
  const int*   src = (const int*)d_in[1];
  const int*   dst = (const int*)d_in[2];
  const int*   gid = (const int*)d_in[3];
  const float* W1  = (const float*)d_in[4];
  const float* b1  = (const float*)d_in[5];
  const float* W2  = (const float*)d_in[6];
  const float* b2  = (const float*)d_in[7];
  const float* W3  = (const float*)d_in[8];
  const float* b3  = (const float*)d_in[9];
  const float* Wv  = (const float*)d_in[10];
  const float* bv  = (const float*)d_in[11];
  const float* Wc  = (const float*)d_in[12];
  const float* bc  = (const float*)d_in[13];
  float* out = (float*)d_out;

  float* ws = (float*)d_ws;
  // bf16 buffers sized 100,156 rows (mfma reads to row 100,031; poison rows
  // beyond NN stay 0xAA = tiny denormal, guarded at all stores)
  ushort_t* hb   = (ushort_t*)ws;                 // 12,820,000 us @ f0..6,410,000
  ushort_t* aggb = (ushort_t*)(ws + 6410000);     // .. f12,820,000
  unsigned* ebuf = (unsigned*)(ws + 12820000);    // 1,600,000 u
  int*   row_ptr = (int*)(ws + 14420000);         // 100,004
  int*   eidx    = (int*)(ws + 14520004);         // 1,600,000
  float* inv     = ws + 16120004;                 // 100,000
  float* num     = ws + 16220004;                 // 16,384
  float* den     = ws + 16236388;                 // 128 (contiguous after num)
  int*   bsumG   = (int*)(ws + 16236516);         // 392
  int*   bbase   = (int*)(ws + 16236908);         // 392
  int*   bfill   = (int*)(ws + 16237300);         // 392
  ushort_t* Wt   = (ushort_t*)(ws + 16237696);    // 98,304 us (16B-aligned)
  ushort_t* W1h = Wt,          *W1l = Wt + 16384;
  ushort_t* W2h = Wt + 32768,  *W2l = Wt + 49152;
  ushort_t* W3h = Wt + 65536,  *W3l = Wt + 81920;

  // ---- bucketed CSR build
  k_zero<<<1, 256, 0, stream>>>((float*)bsumG, 98);  // 392 ints
  f_hist<<<G3, 256, 0, stream>>>(dst, bsumG);
  f_bscan<<<1, 512, 0, stream>>>(bsumG, bbase, bfill, row_ptr);
  f_scatter<<<G3, 256, 0, stream>>>(src, dst, bfill, ebuf);
  f_csr<<<NBUK, 256, 0, stream>>>(ebuf, bbase, row_ptr, inv, eidx);

  // ---- weight transforms + num/den zero (early, off the critical tail)
  k_wconv3<<<192, 256, 0, stream>>>(W1, W2, W3, Wt);
  k_zero<<<17, 256, 0, stream>>>(num, 4128);  // num + den contiguous

  // ---- 3 layers (layer-1 gather reads f32 x directly; layer-3 GEMM fused w/ readout)
  k_gather0<<<12500, 256, 0, stream>>>((const float4*)x, row_ptr, eidx, inv, (uint2*)aggb);
  k_mfma<1><<<1563, 256, 0, stream>>>(aggb, W1h, W1l, b1, hb);
  k_gather<<<6250, 256, 0, stream>>>((uint4*)hb, row_ptr, eidx, inv, (uint4*)aggb);
  k_mfma<1><<<1563, 256, 0, stream>>>(aggb, W2h, W2l, b2, hb);
  k_gather<<<6250, 256, 0, stream>>>((uint4*)hb, row_ptr, eidx, inv, (uint4*)aggb);
  k_mfma_ro<<<1563, 256, 0, stream>>>(aggb, W3h, W3l, b3, gid, Wv, bv, num, den);

  // ---- final
  k_final<<<1, 256, 0, stream>>>(num, den, Wc, bc, out);
}

// Round 14
// 364.584 us; speedup vs baseline: 1.3438x; 1.3438x over previous
//
#include <hip/hip_runtime.h>

#define NN 100000
#define NE 1600000
#define D  128
#define NG 128
#define NO 16
#define NBUK 391   // dst>>8 buckets: 391*256 >= NN
#define BPAD 4608  // padded bucket capacity (mean 4096, +8 sigma)
#define G3 256     // blocks for scatter; G3 * 6250 == NE

typedef unsigned short ushort_t;
typedef __attribute__((ext_vector_type(8))) short short8;
typedef __attribute__((ext_vector_type(4))) float f32x4;

__device__ inline unsigned short f2bf(float f) {  // RNE float->bf16
  unsigned u = __float_as_uint(f);
  unsigned r = u + 0x7fffu + ((u >> 16) & 1u);
  return (unsigned short)(r >> 16);
}
__device__ inline unsigned pk2(float a, float b) {
  return (unsigned)f2bf(a) | ((unsigned)f2bf(b) << 16);
}
__device__ inline float bflo(unsigned q) { return __uint_as_float(q << 16); }
__device__ inline float bfhi(unsigned q) { return __uint_as_float(q & 0xffff0000u); }

// ---------------- init: zero num/den + bucket fill pointers ----------------
__global__ void k_init(float* __restrict__ numden, int* __restrict__ bfill) {
  int i = blockIdx.x * 256 + threadIdx.x;
  if (i < 16512) numden[i] = 0.f;
  if (i < NBUK) bfill[i] = i * BPAD;
}

// ---------------- scatter (src,dst) pairs into padded buckets ----------------
// pack: src (low 20 bits) | dst-low-8 (bits 20..27)
__global__ __launch_bounds__(256) void f_scatter(const int* __restrict__ src,
                                                 const int* __restrict__ dst,
                                                 int* __restrict__ bfill,
                                                 unsigned* __restrict__ ebuf) {
  __shared__ int h[NBUK];
  __shared__ int base[NBUK];
  for (int i = threadIdx.x; i < NBUK; i += 256) h[i] = 0;
  __syncthreads();
  int lo = blockIdx.x * (NE / G3), hi = lo + (NE / G3);
  for (int e = lo + threadIdx.x; e < hi; e += 256) atomicAdd(&h[dst[e] >> 8], 1);
  __syncthreads();
  for (int i = threadIdx.x; i < NBUK; i += 256) {
    int c = h[i];
    base[i] = c ? atomicAdd(&bfill[i], c) : 0;
  }
  __syncthreads();
  for (int i = threadIdx.x; i < NBUK; i += 256) h[i] = 0;
  __syncthreads();
  for (int e = lo + threadIdx.x; e < hi; e += 256) {
    int d = dst[e];
    int b = d >> 8;
    int k = atomicAdd(&h[b], 1);
    ebuf[base[b] + k] = (unsigned)src[e] | ((unsigned)(d & 255) << 20);
  }
}

// ---------------- scan realized bucket counts -> bbase; row_ptr[NN]=NE ----------------
__global__ __launch_bounds__(512) void f_bscan2(const int* __restrict__ bfill,
                                                int* __restrict__ bbase,
                                                int* __restrict__ row_ptr) {
  __shared__ int s[512];
  int t = threadIdx.x;
  int v = (t < NBUK) ? (bfill[t] - t * BPAD) : 0;
  s[t] = v;
  __syncthreads();
  for (int d = 1; d < 512; d <<= 1) {
    int x = (t >= d) ? s[t - d] : 0;
    __syncthreads();
    s[t] += x;
    __syncthreads();
  }
  if (t < NBUK) bbase[t] = s[t] - v;  // exclusive
  if (t == 0) row_ptr[NN] = NE;
}

// one block per bucket: count -> in-block scan -> row_ptr/inv -> CSR fill
__global__ __launch_bounds__(256) void f_csr(const unsigned* __restrict__ ebuf,
                                             const int* __restrict__ bbase,
                                             const int* __restrict__ bfill,
                                             int* __restrict__ row_ptr,
                                             float* __restrict__ inv,
                                             int* __restrict__ eidx) {
  __shared__ int c[256];
  __shared__ int rp[256];
  __shared__ int wsum[4];
  int b = blockIdx.x;
  int t = threadIdx.x;
  c[t] = 0;
  __syncthreads();
  int lo = b * BPAD, hi = bfill[b];
  for (int i = lo + t; i < hi; i += 256) atomicAdd(&c[ebuf[i] >> 20], 1);
  __syncthreads();
  int cnt = c[t];
  int lane = t & 63;
  int incl = cnt;
#pragma unroll
  for (int d = 1; d < 64; d <<= 1) {
    int x = __shfl_up(incl, d);
    if (lane >= d) incl += x;
  }
  if (lane == 63) wsum[t >> 6] = incl;
  __syncthreads();
  int excl = incl - cnt;
  int w = t >> 6;
#pragma unroll
  for (int i = 0; i < 4; i++) excl += (i < w) ? wsum[i] : 0;
  int rpv = bbase[b] + excl;
  rp[t] = rpv;
  int n = (b << 8) + t;
  if (n < NN) {
    row_ptr[n] = rpv;
    inv[n] = 1.f / (float)(cnt + 1);
  }
  c[t] = 0;  // reuse as fill counters
  __syncthreads();
  for (int i = lo + t; i < hi; i += 256) {
    unsigned p = ebuf[i];
    int dl = p >> 20;
    int k = atomicAdd(&c[dl], 1);
    eidx[rp[dl] + k] = (int)(p & 0xFFFFFu);
  }
}

// ---------------- prep: W hi/lo transposed split + x -> bf16 shadow ----------------
__global__ void k_prep(const float* __restrict__ x, uint4* __restrict__ xb,
                       const float* __restrict__ W1, const float* __restrict__ W2,
                       const float* __restrict__ W3, ushort_t* __restrict__ Wt) {
  int bid = blockIdx.x;
  int t = threadIdx.x;
  if (bid < 192) {  // weight transform: 192*256 == 3*D*D
    int idx = bid * 256 + t;
    int m = idx / (D * D);
    int r = idx - m * (D * D);
    const float* W = (m == 0) ? W1 : (m == 1) ? W2 : W3;
    ushort_t* hip = Wt + m * 2 * D * D;
    ushort_t* lop = hip + D * D;
    int k = r >> 7, n = r & 127;
    float w = W[r];
    unsigned short h = f2bf(w);
    float hw = __uint_as_float((unsigned)h << 16);
    hip[n * D + k] = h;
    lop[n * D + k] = f2bf(w - hw);
  } else {  // x conversion: (6442-192)*256 == NN*16
    int i = (bid - 192) * 256 + t;
    if (i < NN * 16) {
      float4 a = ((const float4*)x)[2 * i];
      float4 b = ((const float4*)x)[2 * i + 1];
      uint4 o;
      o.x = pk2(a.x, a.y); o.y = pk2(a.z, a.w);
      o.z = pk2(b.x, b.y); o.w = pk2(b.z, b.w);
      xb[i] = o;
    }
  }
}

// ---------------- gather: aggb[n] = bf16((sum_{u->n} hb[u] + hb[n]) * inv[n]) ----------------
// 16 lanes per node, one uint4 (8 bf16) per lane; 8 row-loads in flight.
// At its measured fabric floor (~188MB @ 3.6TB/s) — do not reshape.
__global__ __launch_bounds__(256) void k_gather(
    const uint4* __restrict__ hb4, const int* __restrict__ rp,
    const int* __restrict__ eidx, const float* __restrict__ inv,
    uint4* __restrict__ aggb4) {
  int t = blockIdx.x * 256 + threadIdx.x;
  int n = t >> 4;
  int l = t & 15;
  if (n >= NN) return;
  int s0 = rp[n], s1 = rp[n + 1];

  uint4 sq = hb4[(size_t)n * 16 + l];  // self
  float A0 = bflo(sq.x), A1 = bfhi(sq.x), A2 = bflo(sq.y), A3 = bfhi(sq.y);
  float A4 = bflo(sq.z), A5 = bfhi(sq.z), A6 = bflo(sq.w), A7 = bfhi(sq.w);
  float B0 = 0, B1 = 0, B2 = 0, B3 = 0, B4 = 0, B5 = 0, B6 = 0, B7 = 0;

  int i = s0;
  for (; i + 8 <= s1; i += 8) {
    int u[8];
    uint4 q[8];
#pragma unroll
    for (int j = 0; j < 8; j++) u[j] = eidx[i + j];
#pragma unroll
    for (int j = 0; j < 8; j++) q[j] = hb4[(size_t)u[j] * 16 + l];
#pragma unroll
    for (int j = 0; j < 8; j += 2) {
      A0 += bflo(q[j].x); A1 += bfhi(q[j].x); A2 += bflo(q[j].y); A3 += bfhi(q[j].y);
      A4 += bflo(q[j].z); A5 += bfhi(q[j].z); A6 += bflo(q[j].w); A7 += bfhi(q[j].w);
      B0 += bflo(q[j + 1].x); B1 += bfhi(q[j + 1].x); B2 += bflo(q[j + 1].y); B3 += bfhi(q[j + 1].y);
      B4 += bflo(q[j + 1].z); B5 += bfhi(q[j + 1].z); B6 += bflo(q[j + 1].w); B7 += bfhi(q[j + 1].w);
    }
  }
  for (; i + 2 <= s1; i += 2) {
    uint4 qa = hb4[(size_t)eidx[i] * 16 + l];
    uint4 qb = hb4[(size_t)eidx[i + 1] * 16 + l];
    A0 += bflo(qa.x); A1 += bfhi(qa.x); A2 += bflo(qa.y); A3 += bfhi(qa.y);
    A4 += bflo(qa.z); A5 += bfhi(qa.z); A6 += bflo(qa.w); A7 += bfhi(qa.w);
    B0 += bflo(qb.x); B1 += bfhi(qb.x); B2 += bflo(qb.y); B3 += bfhi(qb.y);
    B4 += bflo(qb.z); B5 += bfhi(qb.z); B6 += bflo(qb.w); B7 += bfhi(qb.w);
  }
  if (i < s1) {
    uint4 q = hb4[(size_t)eidx[i] * 16 + l];
    A0 += bflo(q.x); A1 += bfhi(q.x); A2 += bflo(q.y); A3 += bfhi(q.y);
    A4 += bflo(q.z); A5 += bfhi(q.z); A6 += bflo(q.w); A7 += bfhi(q.w);
  }

  float iv = inv[n];
  uint4 o;
  o.x = pk2((A0 + B0) * iv, (A1 + B1) * iv);
  o.y = pk2((A2 + B2) * iv, (A3 + B3) * iv);
  o.z = pk2((A4 + B4) * iv, (A5 + B5) * iv);
  o.w = pk2((A6 + B6) * iv, (A7 + B7) * iv);
  aggb4[(size_t)n * 16 + l] = o;
}

// ---------------- MFMA GEMM v4: out = act(A @ (Whi+Wlo) + b) ----------------
// W preloaded to regs as A-operand (frag row = out-col); act staged to swizzled
// LDS, read per-rt as B-operand (frag col = node). Packed 8B stores.
template <int RELU>
__global__ __launch_bounds__(256) void k_mfma(
    const ushort_t* __restrict__ A, const ushort_t* __restrict__ Whi,
    const ushort_t* __restrict__ Wlo, const float* __restrict__ bias,
    ushort_t* __restrict__ outb) {
  __shared__ ushort_t sA[64 * 128];  // 16 KB, XOR slot-swizzled
  int t = threadIdx.x;
  int w = t >> 6;
  int l = t & 63;
  int m = l & 15;
  int seg = l >> 4;
  int R0 = blockIdx.x * 64;

  short8 Wh[2][4], Wl[2][4];
#pragma unroll
  for (int cb2 = 0; cb2 < 2; cb2++) {
    int col = (w * 2 + cb2) * 16 + m;
    const ushort_t* ph = Whi + (size_t)col * D + seg * 8;
    const ushort_t* pl = Wlo + (size_t)col * D + seg * 8;
#pragma unroll
    for (int kc = 0; kc < 4; kc++) {
      Wh[cb2][kc] = *(const short8*)(ph + kc * 32);
      Wl[cb2][kc] = *(const short8*)(pl + kc * 32);
    }
  }

#pragma unroll
  for (int r = 0; r < 4; r++) {
    int q = t + r * 256;
    int row = q >> 4;
    int slot = q & 15;
    float4 v = *(const float4*)(A + (size_t)(R0 + row) * D + slot * 8);
    int sl = slot ^ (row & 15);
    *(float4*)&sA[row * 128 + sl * 8] = v;
  }
  __syncthreads();

#pragma unroll
  for (int rt = 0; rt < 4; rt++) {
    int row = rt * 16 + m;
    short8 act[4];
#pragma unroll
    for (int kc = 0; kc < 4; kc++) {
      int sl = (kc * 4 + seg) ^ m;
      act[kc] = *(const short8*)&sA[row * 128 + sl * 8];
    }
    int node = R0 + row;
#pragma unroll
    for (int cb2 = 0; cb2 < 2; cb2++) {
      f32x4 acc = {0.f, 0.f, 0.f, 0.f};
#pragma unroll
      for (int kc = 0; kc < 4; kc++)
        acc = __builtin_amdgcn_mfma_f32_16x16x32_bf16(Wh[cb2][kc], act[kc], acc, 0, 0, 0);
#pragma unroll
      for (int kc = 0; kc < 4; kc++)
        acc = __builtin_amdgcn_mfma_f32_16x16x32_bf16(Wl[cb2][kc], act[kc], acc, 0, 0, 0);
      if (node < NN) {
        int colb = (w * 2 + cb2) * 16 + seg * 4;
        float4 b4 = *(const float4*)&bias[colb];
        float v0 = acc[0] + b4.x;
        float v1 = acc[1] + b4.y;
        float v2 = acc[2] + b4.z;
        float v3 = acc[3] + b4.w;
        if (RELU) {
          v0 = fmaxf(v0, 0.f); v1 = fmaxf(v1, 0.f);
          v2 = fmaxf(v2, 0.f); v3 = fmaxf(v3, 0.f);
        }
        *(uint2*)&outb[(size_t)node * D + colb] = make_uint2(pk2(v0, v1), pk2(v2, v3));
      }
    }
  }
}

// ---------------- readout: w = sigmoid(h@Wv+bv); num[g] += w*h; den[g] += w ----
__global__ __launch_bounds__(256) void k_readout(
    const uint4* __restrict__ hb4, const int* __restrict__ gid,
    const float* __restrict__ Wv, const float* __restrict__ bv,
    float* __restrict__ num, float* __restrict__ den) {
  __shared__ float wl[256];
  __shared__ int gl[256];
  __shared__ float sWv[128];
  int base = blockIdx.x * 256;
  int t = threadIdx.x;

  if (t < 128) sWv[t] = Wv[t];
  {
    int n = base + t;
    gl[t] = (n < NN) ? gid[n] : -1;
  }
  __syncthreads();

  {
    int n = base + t;
    float s = 0.f;
    if (n < NN) {
      const uint4* row = hb4 + (size_t)n * 16;
#pragma unroll
      for (int h = 0; h < 2; h++) {
        uint4 q[8];
#pragma unroll
        for (int j = 0; j < 8; j++) q[j] = row[h * 8 + j];
#pragma unroll
        for (int j = 0; j < 8; j++) {
          const float* wv = &sWv[(h * 8 + j) * 8];
          s += bflo(q[j].x) * wv[0] + bfhi(q[j].x) * wv[1];
          s += bflo(q[j].y) * wv[2] + bfhi(q[j].y) * wv[3];
          s += bflo(q[j].z) * wv[4] + bfhi(q[j].z) * wv[5];
          s += bflo(q[j].w) * wv[6] + bfhi(q[j].w) * wv[7];
        }
      }
      wl[t] = 1.f / (1.f + expf(-(s + bv[0])));
    } else {
      wl[t] = 0.f;
    }
  }
  __syncthreads();

  int grp = t >> 6;
  int lane = t & 63;
  const unsigned* hbu = (const unsigned*)hb4;
  float a0 = 0.f, a1 = 0.f, wacc = 0.f;
  int cur = -1;
  for (int i0 = 0; i0 < 64; i0 += 4) {
    unsigned q[4];
#pragma unroll
    for (int j = 0; j < 4; j++) {
      int n = base + grp * 64 + i0 + j;
      q[j] = (n < NN) ? hbu[(size_t)n * 64 + lane] : 0u;
    }
#pragma unroll
    for (int j = 0; j < 4; j++) {
      int nl = grp * 64 + i0 + j;
      int g = gl[nl];
      if (g != cur) {
        if (cur >= 0) {
          unsafeAtomicAdd(&num[(size_t)cur * D + 2 * lane], a0);
          unsafeAtomicAdd(&num[(size_t)cur * D + 2 * lane + 1], a1);
          if (lane == 0) unsafeAtomicAdd(&den[cur], wacc);
        }
        cur = g; a0 = 0.f; a1 = 0.f; wacc = 0.f;
      }
      float wv = wl[nl];
      a0 += wv * bflo(q[j]);
      a1 += wv * bfhi(q[j]);
      wacc += wv;
    }
  }
  if (cur >= 0) {
    unsafeAtomicAdd(&num[(size_t)cur * D + 2 * lane], a0);
    unsafeAtomicAdd(&num[(size_t)cur * D + 2 * lane + 1], a1);
    if (lane == 0) unsafeAtomicAdd(&den[cur], wacc);
  }
}

// ---------------- final ----------------
__global__ void k_final(const float* __restrict__ num, const float* __restrict__ den,
                        const float* __restrict__ Wc, const float* __restrict__ bc,
                        float* __restrict__ out) {
  int t = threadIdx.x;
  int o = t & 15;
  for (int g = t >> 4; g < NG; g += 16) {
    float s = 0.f;
    const float* np = num + (size_t)g * D;
#pragma unroll 8
    for (int c = 0; c < D; c++) s += np[c] * Wc[c * NO + o];
    out[g * NO + o] = s / den[g] + bc[o];
  }
}

// ---------------- launch ----------------
extern "C" void kernel_launch(void* const* d_in, const int* in_sizes, int n_in,
                              void* d_out, int out_size, void* d_ws, size_t ws_size,
                              hipStream_t stream) {
  const float* x   = (const float*)d_in[0];
  const int*   src = (const int*)d_in[1];
  const int*   dst = (const int*)d_in[2];
  const int*   gid = (const int*)d_in[3];
  const float* W1  = (const float*)d_in[4];
  const float* b1  = (const float*)d_in[5];
  const float* W2  = (const float*)d_in[6];
  const float* b2  = (const float*)d_in[7];
  const float* W3  = (const float*)d_in[8];
  const float* b3  = (const float*)d_in[9];
  const float* Wv  = (const float*)d_in[10];
  const float* bv  = (const float*)d_in[11];
  const float* Wc  = (const float*)d_in[12];
  const float* bc  = (const float*)d_in[13];
  float* out = (float*)d_out;

  float* ws = (float*)d_ws;
  // bf16 buffers sized 100,156 rows (mfma staging over-reads to row 100,031;
  // poison rows beyond NN stay 0xAA = tiny denormal, guarded at all stores)
  ushort_t* hb   = (ushort_t*)ws;                 // 12,820,000 us @ f0..6,410,000
  ushort_t* aggb = (ushort_t*)(ws + 6410000);     // .. f12,820,000
  unsigned* ebuf = (unsigned*)(ws + 12820000);    // 391*4608 = 1,801,728 u
  int*   row_ptr = (int*)(ws + 14621728);         // 100,004
  int*   eidx    = (int*)(ws + 14721732);         // 1,600,000
  float* inv     = ws + 16321732;                 // 100,000
  float* num     = ws + 16421732;                 // 16,384
  float* den     = ws + 16438116;                 // 128 (contiguous after num)
  int*   bbase   = (int*)(ws + 16438244);         // 392
  int*   bfill   = (int*)(ws + 16438636);         // 392
  ushort_t* Wt   = (ushort_t*)(ws + 16439028);    // 98,304 us (16B-aligned)
  ushort_t* W1h = Wt,          *W1l = Wt + 16384;
  ushort_t* W2h = Wt + 32768,  *W2l = Wt + 49152;
  ushort_t* W3h = Wt + 65536,  *W3l = Wt + 81920;

  // ---- CSR build (padded buckets: no histogram pass)
  k_init<<<65, 256, 0, stream>>>(num, bfill);  // zeroes num+den, inits bfill
  f_scatter<<<G3, 256, 0, stream>>>(src, dst, bfill, ebuf);
  f_bscan2<<<1, 512, 0, stream>>>(bfill, bbase, row_ptr);
  f_csr<<<NBUK, 256, 0, stream>>>(ebuf, bbase, bfill, row_ptr, inv, eidx);

  // ---- weight transforms + x shadow (one kernel)
  k_prep<<<6442, 256, 0, stream>>>(x, (uint4*)hb, W1, W2, W3, Wt);

  // ---- 3 layers, bf16 chain
  k_gather<<<6250, 256, 0, stream>>>((uint4*)hb, row_ptr, eidx, inv, (uint4*)aggb);
  k_mfma<1><<<1563, 256, 0, stream>>>(aggb, W1h, W1l, b1, hb);
  k_gather<<<6250, 256, 0, stream>>>((uint4*)hb, row_ptr, eidx, inv, (uint4*)aggb);
  k_mfma<1><<<1563, 256, 0, stream>>>(aggb, W2h, W2l, b2, hb);
  k_gather<<<6250, 256, 0, stream>>>((uint4*)hb, row_ptr, eidx, inv, (uint4*)aggb);
  k_mfma<0><<<1563, 256, 0, stream>>>(aggb, W3h, W3l, b3, hb);

  // ---- readout
  k_readout<<<391, 256, 0, stream>>>((uint4*)hb, gid, Wv, bv, num, den);
  k_final<<<1, 256, 0, stream>>>(num, den, Wc, bc, out);
}